// Round 1
// baseline (4865.002 us; speedup 1.0000x reference)
//
#include <hip/hip_runtime.h>
#include <math.h>

#define BB     4096
#define NN     32
#define EE     64
#define INDIM  74
#define HH     256
#define GCR    5
#define M1     1024
#define M2     512
#define FDIM   258
#define ADDD   2

// ---------------------------------------------------------------------------
// Kernel 1: one block (256 threads) per graph.
// LDS: Hb[32*256] (h, in-place conv ping) + Tb[32*256] (x-stage/q/p/S/smalls)
// = exactly 64 KB static -> 2 blocks/CU.
//
// Tb overlays (float idx / int idx via Tbi):
//   setup:  Tbi[0..63]=se  Tbi[64..127]=de  Tbi[128..159]=odeg Tbi[160..191]=ideg(->cursor)
//   convs:  Tbi[192..255]=srcl  Tbi[256..288]=rowst  Tb[289..320]=onorm Tb[321..352]=inorm
//   attn:   Tb[0..1054]=S(32x33)  Tb[1056..1087]=v  Tb[1088..1119]=w  Tb[1120..1375]=Wv
// ---------------------------------------------------------------------------

template<int STRIDE, int K, bool RELU>
__device__ __forceinline__ void conv_inplace(
    const float* __restrict__ W, const float* __restrict__ bias,
    float* Hb, const float* onorm, const float* inorm,
    const int* rowst, const int* srcl, int tid)
{
  float acc[NN];
  #pragma unroll
  for (int n = 0; n < NN; ++n) acc[n] = 0.f;

  constexpr int K4 = K & ~3;
  for (int kb = 0; kb < K4; kb += 4) {
    const float w0 = W[(kb + 0) * HH + tid];
    const float w1 = W[(kb + 1) * HH + tid];
    const float w2 = W[(kb + 2) * HH + tid];
    const float w3 = W[(kb + 3) * HH + tid];
    #pragma unroll
    for (int n = 0; n < NN; ++n) {
      const float4 h4 = *(const float4*)&Hb[n * STRIDE + kb];
      acc[n] = fmaf(h4.x, w0, fmaf(h4.y, w1, fmaf(h4.z, w2, fmaf(h4.w, w3, acc[n]))));
    }
  }
  if constexpr (K4 < K) {
    #pragma unroll
    for (int k = K4; k < K; ++k) {
      const float wk = W[k * HH + tid];
      #pragma unroll
      for (int n = 0; n < NN; ++n) acc[n] = fmaf(Hb[n * STRIDE + k], wk, acc[n]);
    }
  }

  __syncthreads();                 // all reads of Hb complete -> safe to overwrite

  const float bj = bias[tid];
  #pragma unroll
  for (int n = 0; n < NN; ++n) Hb[n * HH + tid] = acc[n] * onorm[n];

  // scatter entirely within this thread's column (no cross-thread hazard)
  float outv[NN];
  #pragma unroll
  for (int m = 0; m < NN; ++m) {
    float s = 0.f;
    const int e0 = rowst[m], e1 = rowst[m + 1];
    for (int e = e0; e < e1; ++e) s += Hb[srcl[e] * HH + tid];
    s = fmaf(s, inorm[m], bj);
    outv[m] = RELU ? fmaxf(s, 0.f) : s;
  }
  #pragma unroll
  for (int m = 0; m < NN; ++m) Hb[m * HH + tid] = outv[m];
  __syncthreads();
}

__global__ __launch_bounds__(256, 2)
void gnn_kernel(const float* __restrict__ x, const float* __restrict__ addf,
                const int* __restrict__ src, const int* __restrict__ dst,
                const float* __restrict__ W_in, const float* __restrict__ b_in,
                const float* __restrict__ W_g1, const float* __restrict__ b_g1,
                const float* __restrict__ W_g2, const float* __restrict__ b_g2,
                const float* __restrict__ Wq,  const float* __restrict__ bq,
                const float* __restrict__ Wk,
                const float* __restrict__ Wv,  const float* __restrict__ bv,
                float* __restrict__ F)
{
  __shared__ float Hb[NN * HH];
  __shared__ float Tb[NN * HH];
  int* Tbi = (int*)Tb;

  const int tid = threadIdx.x;
  const int g = blockIdx.x;

  // ---- stage x into Hb at row-stride 80 (zero-pad cols 74..79) ----
  for (int idx = tid; idx < NN * 80; idx += 256) {
    const int r = idx / 80, c = idx - r * 80;
    Hb[idx] = (c < INDIM) ? x[(size_t)g * (NN * INDIM) + r * INDIM + c] : 0.f;
  }
  // ---- edges + degrees ----
  if (tid < 64) Tbi[128 + tid] = 0;           // zero odeg+ideg
  int es = 0, ed = 0;
  if (tid < EE) {
    es = src[(size_t)g * EE + tid];
    ed = dst[(size_t)g * EE + tid];
    Tbi[tid] = es; Tbi[64 + tid] = ed;
  }
  __syncthreads();
  if (tid < EE) {
    atomicAdd(&Tbi[128 + es], 1);
    atomicAdd(&Tbi[160 + ed], 1);
  }
  __syncthreads();
  if (tid < NN) {
    Tb[289 + tid] = 1.f / sqrtf(fmaxf((float)Tbi[128 + tid], 1.f));  // onorm
    Tb[321 + tid] = 1.f / sqrtf(fmaxf((float)Tbi[160 + tid], 1.f));  // inorm
  }
  __syncthreads();
  if (tid == 0) {                              // deterministic CSR build
    int acc = 0;
    #pragma unroll 1
    for (int n = 0; n < NN; ++n) { Tbi[256 + n] = acc; acc += Tbi[160 + n]; Tbi[160 + n] = Tbi[256 + n]; }
    Tbi[256 + NN] = acc;
    #pragma unroll 1
    for (int e = 0; e < EE; ++e) { const int d = Tbi[64 + e]; Tbi[192 + (Tbi[160 + d]++)] = Tbi[e]; }
  }
  __syncthreads();

  const float* onormp = Tb + 289;
  const float* inormp = Tb + 321;
  const int*   rowstp = Tbi + 256;
  const int*   srclp  = Tbi + 192;

  // ---- 11 graph convolutions, all in-place on Hb ----
  conv_inplace<80, INDIM, false>(W_in, b_in, Hb, onormp, inormp, rowstp, srclp, tid);
  for (int L = 0; L < GCR; ++L) {
    conv_inplace<HH, HH, true>(W_g1 + (size_t)L * HH * HH, b_g1 + L * HH, Hb, onormp, inormp, rowstp, srclp, tid);
    conv_inplace<HH, HH, true>(W_g2 + (size_t)L * HH * HH, b_g2 + L * HH, Hb, onormp, inormp, rowstp, srclp, tid);
  }

  // ---- q = h@Wq + bq -> Tb (smalls now dead) ----
  {
    float acc[NN];
    #pragma unroll
    for (int n = 0; n < NN; ++n) acc[n] = 0.f;
    for (int kb = 0; kb < HH; kb += 4) {
      const float w0 = Wq[(kb + 0) * HH + tid];
      const float w1 = Wq[(kb + 1) * HH + tid];
      const float w2 = Wq[(kb + 2) * HH + tid];
      const float w3 = Wq[(kb + 3) * HH + tid];
      #pragma unroll
      for (int n = 0; n < NN; ++n) {
        const float4 h4 = *(const float4*)&Hb[n * HH + kb];
        acc[n] = fmaf(h4.x, w0, fmaf(h4.y, w1, fmaf(h4.z, w2, fmaf(h4.w, w3, acc[n]))));
      }
    }
    const float bqj = bq[tid];
    #pragma unroll
    for (int n = 0; n < NN; ++n) Tb[n * HH + tid] = acc[n] + bqj;
  }
  __syncthreads();

  // ---- p = q @ Wk^T -> Tb in-place (row-constant softmax terms cancel; bk unused) ----
  {
    float acc[NN];
    #pragma unroll
    for (int n = 0; n < NN; ++n) acc[n] = 0.f;
    for (int cb = 0; cb < HH; cb += 4) {
      const float4 w4 = *(const float4*)&Wk[(size_t)tid * HH + cb];
      #pragma unroll
      for (int n = 0; n < NN; ++n) {
        const float4 q4 = *(const float4*)&Tb[n * HH + cb];
        acc[n] = fmaf(q4.x, w4.x, fmaf(q4.y, w4.y, fmaf(q4.z, w4.z, fmaf(q4.w, w4.w, acc[n]))));
      }
    }
    __syncthreads();              // all reads of q complete
    #pragma unroll
    for (int n = 0; n < NN; ++n) Tb[n * HH + tid] = acc[n];
  }
  __syncthreads();

  // ---- S[n][m] = p[n] . h[m]  (4 entries per thread) ----
  {
    const int n  = tid >> 3;
    const int m0 = (tid & 7) << 2;
    float s0 = 0.f, s1 = 0.f, s2 = 0.f, s3 = 0.f;
    for (int cb = 0; cb < HH; cb += 4) {
      const float4 p4 = *(const float4*)&Tb[n * HH + cb];
      const float4 a0 = *(const float4*)&Hb[(m0 + 0) * HH + cb];
      const float4 a1 = *(const float4*)&Hb[(m0 + 1) * HH + cb];
      const float4 a2 = *(const float4*)&Hb[(m0 + 2) * HH + cb];
      const float4 a3 = *(const float4*)&Hb[(m0 + 3) * HH + cb];
      s0 = fmaf(p4.x, a0.x, fmaf(p4.y, a0.y, fmaf(p4.z, a0.z, fmaf(p4.w, a0.w, s0))));
      s1 = fmaf(p4.x, a1.x, fmaf(p4.y, a1.y, fmaf(p4.z, a1.z, fmaf(p4.w, a1.w, s1))));
      s2 = fmaf(p4.x, a2.x, fmaf(p4.y, a2.y, fmaf(p4.z, a2.z, fmaf(p4.w, a2.w, s2))));
      s3 = fmaf(p4.x, a3.x, fmaf(p4.y, a3.y, fmaf(p4.z, a3.z, fmaf(p4.w, a3.w, s3))));
    }
    __syncthreads();              // p dead -> Tb reusable
    Tb[n * 33 + m0 + 0] = s0;
    Tb[n * 33 + m0 + 1] = s1;
    Tb[n * 33 + m0 + 2] = s2;
    Tb[n * 33 + m0 + 3] = s3;
    Tb[1120 + tid] = Wv[tid];     // stage Wv
  }
  __syncthreads();

  // ---- v[m] = h[m].Wv + bv  (lane-skewed to dodge 32-way conflicts) ----
  if (tid < NN) {
    float s = 0.f;
    for (int cc = 0; cc < HH; ++cc) {
      const int c = (cc + tid) & (HH - 1);
      s += Hb[tid * HH + c] * Tb[1120 + c];
    }
    Tb[1056 + tid] = s + bv[0];
  }
  __syncthreads();

  // ---- row softmax fused with w = attn @ v ----
  if (tid < NN) {
    float mx = -1e30f;
    #pragma unroll 1
    for (int m = 0; m < NN; ++m) mx = fmaxf(mx, Tb[tid * 33 + m]);
    float se = 0.f, sv = 0.f;
    #pragma unroll 1
    for (int m = 0; m < NN; ++m) {
      const float e = expf(Tb[tid * 33 + m] - mx);
      se += e;
      sv = fmaf(e, Tb[1056 + m], sv);
    }
    Tb[1088 + tid] = sv / se;
  }
  __syncthreads();

  // ---- feats = h^T @ w, append add_features ----
  {
    float f = 0.f;
    #pragma unroll
    for (int m = 0; m < NN; ++m) f = fmaf(Hb[m * HH + tid], Tb[1088 + m], f);
    F[(size_t)g * FDIM + tid] = f;
    if (tid < ADDD) F[(size_t)g * FDIM + HH + tid] = addf[(size_t)g * ADDD + tid];
  }
}

// ---------------------------------------------------------------------------
// Kernel 2: batched MLP, 8 rows per block, all layers fused via LDS overlay.
// sm[8*1024] = 32 KB: Ftile(stride 260) -> z1[8][1024] -> z2[8][512]
// ---------------------------------------------------------------------------
#define MR 8
__global__ __launch_bounds__(256, 2)
void mlp_kernel(const float* __restrict__ F,
                const float* __restrict__ W1, const float* __restrict__ b1,
                const float* __restrict__ W2, const float* __restrict__ b2,
                const float* __restrict__ W3, const float* __restrict__ b3,
                float* __restrict__ out)
{
  __shared__ float sm[MR * M1];
  const int tid = threadIdx.x;
  const int r0 = blockIdx.x * MR;

  for (int idx = tid; idx < MR * FDIM; idx += 256) {
    const int r = idx / FDIM, c = idx - r * FDIM;
    sm[r * 260 + c] = F[(size_t)(r0 + r) * FDIM + c];
  }
  __syncthreads();

  // layer 1: 258 -> 1024, leaky
  float a1[4][MR];
  #pragma unroll
  for (int qg = 0; qg < 4; ++qg)
    #pragma unroll
    for (int r = 0; r < MR; ++r) a1[qg][r] = 0.f;
  for (int i = 0; i < FDIM; ++i) {
    float w[4];
    #pragma unroll
    for (int qg = 0; qg < 4; ++qg) w[qg] = W1[(size_t)i * M1 + tid + 256 * qg];
    #pragma unroll
    for (int r = 0; r < MR; ++r) {
      const float fv = sm[r * 260 + i];
      #pragma unroll
      for (int qg = 0; qg < 4; ++qg) a1[qg][r] = fmaf(fv, w[qg], a1[qg][r]);
    }
  }
  __syncthreads();
  #pragma unroll
  for (int qg = 0; qg < 4; ++qg) {
    const float bb = b1[tid + 256 * qg];
    #pragma unroll
    for (int r = 0; r < MR; ++r) {
      const float z = a1[qg][r] + bb;
      sm[r * M1 + tid + 256 * qg] = fmaxf(z, 0.01f * z);
    }
  }
  __syncthreads();

  // layer 2: 1024 -> 512, leaky
  float a2[2][MR];
  #pragma unroll
  for (int qg = 0; qg < 2; ++qg)
    #pragma unroll
    for (int r = 0; r < MR; ++r) a2[qg][r] = 0.f;
  for (int i = 0; i < M1; ++i) {
    float w[2];
    #pragma unroll
    for (int qg = 0; qg < 2; ++qg) w[qg] = W2[(size_t)i * M2 + tid + 256 * qg];
    #pragma unroll
    for (int r = 0; r < MR; ++r) {
      const float zv = sm[r * M1 + i];
      #pragma unroll
      for (int qg = 0; qg < 2; ++qg) a2[qg][r] = fmaf(zv, w[qg], a2[qg][r]);
    }
  }
  __syncthreads();
  #pragma unroll
  for (int qg = 0; qg < 2; ++qg) {
    const float bb = b2[tid + 256 * qg];
    #pragma unroll
    for (int r = 0; r < MR; ++r) {
      const float z = a2[qg][r] + bb;
      sm[r * M2 + tid + 256 * qg] = fmaxf(z, 0.01f * z);
    }
  }
  __syncthreads();

  // layer 3: 512 -> 1 ; 4 waves x 2 rows, shuffle-reduce
  const int lane = tid & 63, wid = tid >> 6;
  float wreg[8];
  #pragma unroll
  for (int q = 0; q < 8; ++q) wreg[q] = W3[lane + 64 * q];
  #pragma unroll
  for (int rr = 0; rr < 2; ++rr) {
    const int r = wid * 2 + rr;
    float s = 0.f;
    #pragma unroll
    for (int q = 0; q < 8; ++q) s = fmaf(sm[r * M2 + lane + 64 * q], wreg[q], s);
    #pragma unroll
    for (int off = 32; off; off >>= 1) s += __shfl_down(s, off);
    if (lane == 0) out[r0 + r] = s + b3[0];
  }
}

// ---------------------------------------------------------------------------
extern "C" void kernel_launch(void* const* d_in, const int* in_sizes, int n_in,
                              void* d_out, int out_size, void* d_ws, size_t ws_size,
                              hipStream_t stream) {
  (void)in_sizes; (void)n_in; (void)out_size; (void)ws_size;
  const float* x    = (const float*)d_in[0];
  const float* addf = (const float*)d_in[1];
  const int*   src  = (const int*)d_in[2];
  const int*   dst  = (const int*)d_in[3];
  const float* W_in = (const float*)d_in[4];
  const float* b_in = (const float*)d_in[5];
  const float* W_g1 = (const float*)d_in[6];
  const float* b_g1 = (const float*)d_in[7];
  const float* W_g2 = (const float*)d_in[8];
  const float* b_g2 = (const float*)d_in[9];
  const float* Wq   = (const float*)d_in[10];
  const float* bq   = (const float*)d_in[11];
  const float* Wk   = (const float*)d_in[12];
  // d_in[13] = bk : cancels exactly in softmax (row-constant), unused
  const float* Wv   = (const float*)d_in[14];
  const float* bv   = (const float*)d_in[15];
  const float* W1   = (const float*)d_in[16];
  const float* b1   = (const float*)d_in[17];
  const float* W2   = (const float*)d_in[18];
  const float* b2   = (const float*)d_in[19];
  const float* W3   = (const float*)d_in[20];
  const float* b3   = (const float*)d_in[21];
  float* out = (float*)d_out;

  float* F = (float*)d_ws;   // [4096, 258] fp32 = 4.2 MB scratch

  gnn_kernel<<<dim3(BB), dim3(256), 0, stream>>>(
      x, addf, src, dst, W_in, b_in, W_g1, b_g1, W_g2, b_g2,
      Wq, bq, Wk, Wv, bv, F);
  mlp_kernel<<<dim3(BB / MR), dim3(256), 0, stream>>>(
      F, W1, b1, W2, b2, W3, b3, out);
}

// Round 2
// 1548.227 us; speedup vs baseline: 3.1423x; 3.1423x over previous
//
#include <hip/hip_runtime.h>
#include <math.h>

#define BB     4096
#define NN     32
#define EE     64
#define INDIM  74
#define HH     256
#define GCR    5
#define M1     1024
#define M2     512
#define FDIM   258
#define ADDD   2

typedef __attribute__((ext_vector_type(8))) short short8_t;
typedef __attribute__((ext_vector_type(4))) float float4_t;

#define MFMA16(a, b, c) __builtin_amdgcn_mfma_f32_16x16x32_bf16((a), (b), (c), 0, 0, 0)

// ---- ws layout (bytes) ----
#define WS_F      0               // F [4096][258] f32 = 4,227,072
#define WS_WQK    4227072         // Wqk fp32 [256][256] = 262,144
#define WS_TVEC   4489216         // tvec fp32 [256] = 1,024
#define WS_PK     4490240         // packed bf16 hi/lo fragments
// packed offsets in ushort units from PK base:
//   W_in:  hi @ 0, lo @ 24576            (KS=3, 16*3*64*8 = 24576 el each)
//   G[L] (L=0..9: g1[0..4], g2[0..4]): hi @ 49152 + L*131072, lo = hi + 65536
//   Wqk:   hi @ 49152 + 10*131072 = 1359872, lo = +65536
#define PK_WIN_HI 0
#define PK_WIN_LO 24576
#define PK_G_BASE 49152
#define PK_G_STRIDE 131072
#define PK_WQK_HI 1359872
#define PK_WQK_LO (1359872 + 65536)

__device__ __forceinline__ unsigned short f2bf(float f) {
  union { float f; unsigned int u; } c; c.f = f;
  unsigned int u = c.u;
  return (unsigned short)((u + 0x7FFFu + ((u >> 16) & 1u)) >> 16);
}
__device__ __forceinline__ float bf2f(unsigned short h) {
  union { unsigned int u; float f; } c; c.u = ((unsigned int)h) << 16;
  return c.f;
}

// ---------------------------------------------------------------------------
// Prep 1: Wqk = Wq @ Wk^T (fp32), tvec = Wk @ bq
// ---------------------------------------------------------------------------
__global__ void prep1_kernel(const float* __restrict__ Wq, const float* __restrict__ Wk,
                             const float* __restrict__ bq,
                             float* __restrict__ wqkf, float* __restrict__ tvec) {
  const int i = blockIdx.x, j = threadIdx.x;
  if (i < 256) {
    __shared__ float qrow[256];
    qrow[j] = Wq[i * 256 + j];
    __syncthreads();
    float s = 0.f;
    for (int c = 0; c < 256; ++c) s = fmaf(qrow[c], Wk[j * 256 + c], s);
    wqkf[i * 256 + j] = s;
  } else {
    float s = 0.f;
    for (int c = 0; c < 256; ++c) s = fmaf(Wk[j * 256 + c], bq[c], s);
    tvec[j] = s;
  }
}

// ---------------------------------------------------------------------------
// Prep 2: pack weights into MFMA B-fragment order, split hi/lo bf16.
// dst chunk (8 elems): local = (nt*KS + ks)*64 + lane; elem i:
//   k = ks*32 + (lane>>4)*8 + i ; j = nt*16 + (lane&15) ; src = W[k*256+j]
// ---------------------------------------------------------------------------
template<int KS, int KREAL>
__device__ __forceinline__ void pack_one(const float* __restrict__ S,
                                         unsigned short* __restrict__ hi,
                                         unsigned short* __restrict__ lo, int local) {
  const int l = local & 63;
  const int nk = local >> 6;
  const int ks = nk % KS;
  const int nt = nk / KS;
  const int j = nt * 16 + (l & 15);
  const int kbase = ks * 32 + (l >> 4) * 8;
  short8_t h8, l8;
  #pragma unroll
  for (int i = 0; i < 8; ++i) {
    const int k = kbase + i;
    const float v = (k < KREAL) ? S[k * 256 + j] : 0.f;
    const unsigned short hb = f2bf(v);
    const unsigned short lb = f2bf(v - bf2f(hb));
    h8[i] = (short)hb; l8[i] = (short)lb;
  }
  *(short8_t*)(hi + (size_t)local * 8) = h8;
  *(short8_t*)(lo + (size_t)local * 8) = l8;
}

__global__ void prep2_kernel(const float* __restrict__ W_in,
                             const float* __restrict__ W_g1, const float* __restrict__ W_g2,
                             const float* __restrict__ wqkf, unsigned short* __restrict__ pk) {
  const int cid = blockIdx.x * 256 + threadIdx.x;   // one 8-elem chunk per thread
  if (cid < 3072) {
    pack_one<3, 74>(W_in, pk + PK_WIN_HI, pk + PK_WIN_LO, cid);
  } else {
    const int m = (cid - 3072) >> 13;               // 0..10
    const int local = (cid - 3072) & 8191;
    unsigned short* hi; const float* S;
    if (m < 10) {
      hi = pk + PK_G_BASE + (size_t)m * PK_G_STRIDE;
      S = (m < 5) ? (W_g1 + (size_t)m * 65536) : (W_g2 + (size_t)(m - 5) * 65536);
    } else {
      hi = pk + PK_WQK_HI;
      S = wqkf;
    }
    pack_one<8, 256>(S, hi, hi + 65536, local);
  }
}

// ---------------------------------------------------------------------------
// GNN kernel: one block (256 thr) per graph. split-bf16 MFMA everywhere.
// LDS: Hhi/Hlo [32][256] bf16 (swizzled)  = 32 KB
//      Tb      [32][128] f32  (swizzled)  = 16 KB   (conv raw D halves / u' hi+lo)
//      Sb      1312 f32                   = 5.25 KB (S, norms, CSR, v, w)
// ---------------------------------------------------------------------------

// Hb swizzled byte offset: row-stride 512B, XOR (row&7)<<4
__device__ __forceinline__ int hoff(int row, int col) {
  return row * 512 + (((col) * 2) ^ ((row & 7) << 4));
}
// Tb (f32 [32][128]) swizzled byte offset
__device__ __forceinline__ int toff(int row, int c) {
  return row * 512 + (((c) * 4) ^ ((row & 7) << 4));
}
// U (ushort [32][128]) swizzled byte offset
__device__ __forceinline__ int uoff(int row, int c) {
  return row * 256 + (((c) * 2) ^ ((row & 7) << 4));
}

__device__ __forceinline__ void wrH(char* HhiB, char* HloB, int row, int col, float v) {
  const unsigned short hb = f2bf(v);
  const unsigned short lb = f2bf(v - bf2f(hb));
  const int off = hoff(row, col);
  *(unsigned short*)(HhiB + off) = hb;
  *(unsigned short*)(HloB + off) = lb;
}

template<int KS>
__device__ __forceinline__ void conv_step(
    char* HhiB, char* HloB, float* Tb,
    const unsigned short* __restrict__ Whi, const unsigned short* __restrict__ Wlo,
    const float* __restrict__ bias,
    const float* onorm, const float* inorm, const int* rowst, const int* srcl,
    int tid, int lane, int wv, bool relu, bool scale)
{
  float hold[16];
  #pragma unroll
  for (int p = 0; p < 2; ++p) {
    // ---- MFMA phase p: compute D for output cols [p*128, p*128+128) ----
    float4_t acc[2][2];
    #pragma unroll
    for (int a = 0; a < 2; ++a)
      #pragma unroll
      for (int b = 0; b < 2; ++b) acc[a][b] = (float4_t){0.f, 0.f, 0.f, 0.f};

    #pragma unroll
    for (int ks = 0; ks < KS; ++ks) {
      const int col0 = ks * 32 + (lane >> 4) * 8;
      const int r0 = (lane & 15), r1 = 16 + r0;
      const int o0 = hoff(r0, col0), o1 = hoff(r1, col0);
      const short8_t ah0 = *(const short8_t*)(HhiB + o0);
      const short8_t al0 = *(const short8_t*)(HloB + o0);
      const short8_t ah1 = *(const short8_t*)(HhiB + o1);
      const short8_t al1 = *(const short8_t*)(HloB + o1);
      #pragma unroll
      for (int ntl = 0; ntl < 2; ++ntl) {
        const int nt = p * 8 + wv * 2 + ntl;
        const size_t wo = ((size_t)(nt * KS + ks) * 64 + lane) * 8;
        const short8_t bh = *(const short8_t*)(Whi + wo);
        const short8_t bl = *(const short8_t*)(Wlo + wo);
        acc[0][ntl] = MFMA16(ah0, bh, acc[0][ntl]);
        acc[0][ntl] = MFMA16(ah0, bl, acc[0][ntl]);
        acc[0][ntl] = MFMA16(al0, bh, acc[0][ntl]);
        acc[1][ntl] = MFMA16(ah1, bh, acc[1][ntl]);
        acc[1][ntl] = MFMA16(ah1, bl, acc[1][ntl]);
        acc[1][ntl] = MFMA16(al1, bh, acc[1][ntl]);
      }
    }
    // ---- write raw D into Tb (prior readers of Tb are barrier-separated) ----
    #pragma unroll
    for (int mt = 0; mt < 2; ++mt)
      #pragma unroll
      for (int ntl = 0; ntl < 2; ++ntl) {
        const int c = (wv * 2 + ntl) * 16 + (lane & 15);
        #pragma unroll
        for (int jj = 0; jj < 4; ++jj) {
          const int row = mt * 16 + 4 * (lane >> 4) + jj;
          *(float*)((char*)Tb + toff(row, c)) = acc[mt][ntl][jj];
        }
      }
    __syncthreads();   // (i) D visible; also all Hb A-reads of this phase done

    // ---- scatter phase p: thread -> col p*128 + (tid&127), rows rh*16.. ----
    const int jl = tid & 127;
    const int j = p * 128 + jl;
    const int rh = tid >> 7;
    const float bj = bias[j];
    float hv[16];
    #pragma unroll
    for (int mi = 0; mi < 16; ++mi) {
      const int m = rh * 16 + mi;
      float s = 0.f;
      const int e0 = rowst[m], e1 = rowst[m + 1];
      for (int e = e0; e < e1; ++e) {
        const int sr = srcl[e];
        s += *(const float*)((const char*)Tb + toff(sr, jl));
      }
      float t = fmaf(s, inorm[m], bj);
      if (relu) t = fmaxf(t, 0.f);
      hv[mi] = scale ? t * onorm[m] : t;
    }
    if (p == 0) {
      #pragma unroll
      for (int mi = 0; mi < 16; ++mi) hold[mi] = hv[mi];
      __syncthreads();  // (ii) scatter0 Tb reads done before D1 writes
    } else {
      // all Hb reads (MFMA1) finished at (i); safe to overwrite h in place
      #pragma unroll
      for (int mi = 0; mi < 16; ++mi) wrH(HhiB, HloB, rh * 16 + mi, jl, hold[mi]);
      #pragma unroll
      for (int mi = 0; mi < 16; ++mi) wrH(HhiB, HloB, rh * 16 + mi, 128 + jl, hv[mi]);
      __syncthreads();  // (iii) new h visible; Tb free
    }
  }
}

__global__ __launch_bounds__(256, 2)
void gnn_kernel(const float* __restrict__ x, const float* __restrict__ addf,
                const int* __restrict__ src, const int* __restrict__ dst,
                const float* __restrict__ b_in,
                const float* __restrict__ b_g1, const float* __restrict__ b_g2,
                const float* __restrict__ Wvp, const float* __restrict__ bv,
                const unsigned short* __restrict__ pk,
                const float* __restrict__ tvec,
                float* __restrict__ F)
{
  __shared__ __align__(16) unsigned short Hhi[NN * HH];
  __shared__ __align__(16) unsigned short Hlo[NN * HH];
  __shared__ __align__(16) float Tb[NN * 128];
  __shared__ float Sb[1312];

  char* HhiB = (char*)Hhi;
  char* HloB = (char*)Hlo;
  int* Sbi = (int*)Sb;
  float* onorm = Sb + 1056;
  float* inorm = Sb + 1088;
  int*   rowst = Sbi + 1120;   // 33
  int*   srcl  = Sbi + 1153;   // 64
  float* vS    = Sb + 1217;    // 32
  float* wS    = Sb + 1249;    // 32

  const int tid = threadIdx.x;
  const int lane = tid & 63;
  const int wv = tid >> 6;
  const int g = blockIdx.x;

  // ---- setup: edges, degrees, norms, CSR (scratch in Sb[0..191] ints) ----
  if (tid < 64) Sbi[128 + tid] = 0;        // odeg @128, ideg @160
  int es = 0, ed = 0;
  if (tid < EE) {
    es = src[(size_t)g * EE + tid];
    ed = dst[(size_t)g * EE + tid];
    Sbi[tid] = es; Sbi[64 + tid] = ed;
  }
  __syncthreads();
  if (tid < EE) {
    atomicAdd(&Sbi[128 + es], 1);
    atomicAdd(&Sbi[160 + ed], 1);
  }
  __syncthreads();
  if (tid < NN) {
    onorm[tid] = 1.f / sqrtf(fmaxf((float)Sbi[128 + tid], 1.f));
    inorm[tid] = 1.f / sqrtf(fmaxf((float)Sbi[160 + tid], 1.f));
  }
  __syncthreads();
  if (tid == 0) {
    int acc = 0;
    #pragma unroll 1
    for (int n = 0; n < NN; ++n) { rowst[n] = acc; acc += Sbi[160 + n]; Sbi[160 + n] = rowst[n]; }
    rowst[NN] = acc;
    #pragma unroll 1
    for (int e = 0; e < EE; ++e) { const int d = Sbi[64 + e]; srcl[Sbi[160 + d]++] = Sbi[e]; }
  }
  __syncthreads();

  // ---- stage x*onorm into Hb (cols 0..95, zero-pad 74..95), split hi/lo ----
  for (int idx = tid; idx < NN * 96; idx += 256) {
    const int r = idx / 96, c = idx - r * 96;
    const float vx = (c < INDIM) ? x[(size_t)g * (NN * INDIM) + r * INDIM + c] * onorm[r] : 0.f;
    wrH(HhiB, HloB, r, c, vx);
  }
  __syncthreads();

  // ---- 11 graph convolutions ----
  conv_step<3>(HhiB, HloB, Tb, pk + PK_WIN_HI, pk + PK_WIN_LO, b_in,
               onorm, inorm, rowst, srcl, tid, lane, wv, false, true);
  #pragma unroll 1
  for (int L = 0; L < GCR; ++L) {
    const unsigned short* h1 = pk + PK_G_BASE + (size_t)L * PK_G_STRIDE;
    conv_step<8>(HhiB, HloB, Tb, h1, h1 + 65536, b_g1 + L * HH,
                 onorm, inorm, rowst, srcl, tid, lane, wv, true, true);
    const unsigned short* h2 = pk + PK_G_BASE + (size_t)(5 + L) * PK_G_STRIDE;
    conv_step<8>(HhiB, HloB, Tb, h2, h2 + 65536, b_g2 + L * HH,
                 onorm, inorm, rowst, srcl, tid, lane, wv, true, L != GCR - 1);
  }
  // Hb now holds final h (unscaled, relu'd), split hi/lo.

  // ---- attention: u' = h@Wqk + tvec ; S = u'@h^T ; softmax ; w ; feats ----
  unsigned short* Uhi = (unsigned short*)Tb;       // [32][128]
  unsigned short* Ulo = Uhi + 4096;
  const unsigned short* Qhi = pk + PK_WQK_HI;
  const unsigned short* Qlo = pk + PK_WQK_LO;

  float4_t sacc = (float4_t){0.f, 0.f, 0.f, 0.f};
  const int smt = wv >> 1, snt = wv & 1;

  #pragma unroll
  for (int p = 0; p < 2; ++p) {
    // u' MFMA phase p
    float4_t uacc[2][2];
    #pragma unroll
    for (int a = 0; a < 2; ++a)
      #pragma unroll
      for (int b = 0; b < 2; ++b) uacc[a][b] = (float4_t){0.f, 0.f, 0.f, 0.f};
    #pragma unroll
    for (int ks = 0; ks < 8; ++ks) {
      const int col0 = ks * 32 + (lane >> 4) * 8;
      const int r0 = (lane & 15), r1 = 16 + r0;
      const int o0 = hoff(r0, col0), o1 = hoff(r1, col0);
      const short8_t ah0 = *(const short8_t*)(HhiB + o0);
      const short8_t al0 = *(const short8_t*)(HloB + o0);
      const short8_t ah1 = *(const short8_t*)(HhiB + o1);
      const short8_t al1 = *(const short8_t*)(HloB + o1);
      #pragma unroll
      for (int ntl = 0; ntl < 2; ++ntl) {
        const int nt = p * 8 + wv * 2 + ntl;
        const size_t wo = ((size_t)(nt * 8 + ks) * 64 + lane) * 8;
        const short8_t bh = *(const short8_t*)(Qhi + wo);
        const short8_t bl = *(const short8_t*)(Qlo + wo);
        uacc[0][ntl] = MFMA16(ah0, bh, uacc[0][ntl]);
        uacc[0][ntl] = MFMA16(ah0, bl, uacc[0][ntl]);
        uacc[0][ntl] = MFMA16(al0, bh, uacc[0][ntl]);
        uacc[1][ntl] = MFMA16(ah1, bh, uacc[1][ntl]);
        uacc[1][ntl] = MFMA16(ah1, bl, uacc[1][ntl]);
        uacc[1][ntl] = MFMA16(al1, bh, uacc[1][ntl]);
      }
    }
    if (p == 1) __syncthreads();   // S(p=0) finished reading U0 before overwrite
    // write u' (+tvec), split hi/lo, into U (Tb)
    #pragma unroll
    for (int mt = 0; mt < 2; ++mt)
      #pragma unroll
      for (int ntl = 0; ntl < 2; ++ntl) {
        const int cl = (wv * 2 + ntl) * 16 + (lane & 15);
        const float tv = tvec[p * 128 + cl];
        #pragma unroll
        for (int jj = 0; jj < 4; ++jj) {
          const int row = mt * 16 + 4 * (lane >> 4) + jj;
          const float v = uacc[mt][ntl][jj] + tv;
          const unsigned short hb = f2bf(v);
          const unsigned short lb = f2bf(v - bf2f(hb));
          const int off = uoff(row, cl);
          *(unsigned short*)((char*)Uhi + off) = hb;
          *(unsigned short*)((char*)Ulo + off) = lb;
        }
      }
    __syncthreads();

    // S partial: k in [p*128, p*128+128)
    #pragma unroll
    for (int ksl = 0; ksl < 4; ++ksl) {
      const int ra = smt * 16 + (lane & 15);
      const int cl0 = ksl * 32 + (lane >> 4) * 8;
      const int oa = uoff(ra, cl0);
      const short8_t ah = *(const short8_t*)((char*)Uhi + oa);
      const short8_t al = *(const short8_t*)((char*)Ulo + oa);
      const int rb = snt * 16 + (lane & 15);
      const int kg = p * 128 + cl0;
      const int ob = hoff(rb, kg);
      const short8_t bh = *(const short8_t*)(HhiB + ob);
      const short8_t bl = *(const short8_t*)(HloB + ob);
      sacc = MFMA16(ah, bh, sacc);
      sacc = MFMA16(ah, bl, sacc);
      sacc = MFMA16(al, bh, sacc);
    }
    if (p == 0) {
      // v[m] = h[m].Wv + bv   (8 lanes per row, shfl reduce) — overlaps phase gap
      const int row = tid >> 3;
      const int c0 = (tid & 7) * 32;
      float s = 0.f;
      for (int cc = 0; cc < 32; ++cc) {
        const int c = c0 + cc;
        const int off = hoff(row, c);
        const float hvv = bf2f(*(unsigned short*)(HhiB + off)) +
                          bf2f(*(unsigned short*)(HloB + off));
        s = fmaf(hvv, Wvp[c], s);
      }
      s += __shfl_xor(s, 1); s += __shfl_xor(s, 2); s += __shfl_xor(s, 4);
      if ((tid & 7) == 0) vS[row] = s + bv[0];
    }
  }
  // write S to Sb
  #pragma unroll
  for (int jj = 0; jj < 4; ++jj) {
    const int row = smt * 16 + 4 * (lane >> 4) + jj;
    const int col = snt * 16 + (lane & 15);
    Sb[row * 33 + col] = sacc[jj];
  }
  __syncthreads();

  // ---- row softmax fused with w = attn @ v ----
  if (tid < NN) {
    float mx = -1e30f;
    #pragma unroll 1
    for (int m = 0; m < NN; ++m) mx = fmaxf(mx, Sb[tid * 33 + m]);
    float se = 0.f, sv = 0.f;
    #pragma unroll 1
    for (int m = 0; m < NN; ++m) {
      const float e = expf(Sb[tid * 33 + m] - mx);
      se += e;
      sv = fmaf(e, vS[m], sv);
    }
    wS[tid] = sv / se;
  }
  __syncthreads();

  // ---- feats = h^T @ w ----
  {
    float f = 0.f;
    #pragma unroll
    for (int m = 0; m < NN; ++m) {
      const int off = hoff(m, tid);
      const float hvv = bf2f(*(unsigned short*)(HhiB + off)) +
                        bf2f(*(unsigned short*)(HloB + off));
      f = fmaf(hvv, wS[m], f);
    }
    F[(size_t)g * FDIM + tid] = f;
    if (tid < ADDD) F[(size_t)g * FDIM + HH + tid] = addf[(size_t)g * ADDD + tid];
  }
}

// ---------------------------------------------------------------------------
// Kernel 2: batched MLP (unchanged this round)
// ---------------------------------------------------------------------------
#define MR 8
__global__ __launch_bounds__(256, 2)
void mlp_kernel(const float* __restrict__ F,
                const float* __restrict__ W1, const float* __restrict__ b1,
                const float* __restrict__ W2, const float* __restrict__ b2,
                const float* __restrict__ W3, const float* __restrict__ b3,
                float* __restrict__ out)
{
  __shared__ float sm[MR * M1];
  const int tid = threadIdx.x;
  const int r0 = blockIdx.x * MR;

  for (int idx = tid; idx < MR * FDIM; idx += 256) {
    const int r = idx / FDIM, c = idx - r * FDIM;
    sm[r * 260 + c] = F[(size_t)(r0 + r) * FDIM + c];
  }
  __syncthreads();

  float a1[4][MR];
  #pragma unroll
  for (int qg = 0; qg < 4; ++qg)
    #pragma unroll
    for (int r = 0; r < MR; ++r) a1[qg][r] = 0.f;
  for (int i = 0; i < FDIM; ++i) {
    float w[4];
    #pragma unroll
    for (int qg = 0; qg < 4; ++qg) w[qg] = W1[(size_t)i * M1 + tid + 256 * qg];
    #pragma unroll
    for (int r = 0; r < MR; ++r) {
      const float fv = sm[r * 260 + i];
      #pragma unroll
      for (int qg = 0; qg < 4; ++qg) a1[qg][r] = fmaf(fv, w[qg], a1[qg][r]);
    }
  }
  __syncthreads();
  #pragma unroll
  for (int qg = 0; qg < 4; ++qg) {
    const float bb = b1[tid + 256 * qg];
    #pragma unroll
    for (int r = 0; r < MR; ++r) {
      const float z = a1[qg][r] + bb;
      sm[r * M1 + tid + 256 * qg] = fmaxf(z, 0.01f * z);
    }
  }
  __syncthreads();

  float a2[2][MR];
  #pragma unroll
  for (int qg = 0; qg < 2; ++qg)
    #pragma unroll
    for (int r = 0; r < MR; ++r) a2[qg][r] = 0.f;
  for (int i = 0; i < M1; ++i) {
    float w[2];
    #pragma unroll
    for (int qg = 0; qg < 2; ++qg) w[qg] = W2[(size_t)i * M2 + tid + 256 * qg];
    #pragma unroll
    for (int r = 0; r < MR; ++r) {
      const float zv = sm[r * M1 + i];
      #pragma unroll
      for (int qg = 0; qg < 2; ++qg) a2[qg][r] = fmaf(zv, w[qg], a2[qg][r]);
    }
  }
  __syncthreads();
  #pragma unroll
  for (int qg = 0; qg < 2; ++qg) {
    const float bb = b2[tid + 256 * qg];
    #pragma unroll
    for (int r = 0; r < MR; ++r) {
      const float z = a2[qg][r] + bb;
      sm[r * M2 + tid + 256 * qg] = fmaxf(z, 0.01f * z);
    }
  }
  __syncthreads();

  const int lane = tid & 63, wid = tid >> 6;
  float wreg[8];
  #pragma unroll
  for (int q = 0; q < 8; ++q) wreg[q] = W3[lane + 64 * q];
  #pragma unroll
  for (int rr = 0; rr < 2; ++rr) {
    const int r = wid * 2 + rr;
    float s = 0.f;
    #pragma unroll
    for (int q = 0; q < 8; ++q) s = fmaf(sm[r * M2 + lane + 64 * q], wreg[q], s);
    #pragma unroll
    for (int off = 32; off; off >>= 1) s += __shfl_down(s, off);
    if (lane == 0) out[r0 + r] = s + b3[0];
  }
}

// ---------------------------------------------------------------------------
extern "C" void kernel_launch(void* const* d_in, const int* in_sizes, int n_in,
                              void* d_out, int out_size, void* d_ws, size_t ws_size,
                              hipStream_t stream) {
  (void)in_sizes; (void)n_in; (void)out_size; (void)ws_size;
  const float* x    = (const float*)d_in[0];
  const float* addf = (const float*)d_in[1];
  const int*   src  = (const int*)d_in[2];
  const int*   dst  = (const int*)d_in[3];
  const float* W_in = (const float*)d_in[4];
  const float* b_in = (const float*)d_in[5];
  const float* W_g1 = (const float*)d_in[6];
  const float* b_g1 = (const float*)d_in[7];
  const float* W_g2 = (const float*)d_in[8];
  const float* b_g2 = (const float*)d_in[9];
  const float* Wq   = (const float*)d_in[10];
  const float* bq   = (const float*)d_in[11];
  const float* Wk   = (const float*)d_in[12];
  // d_in[13] = bk : cancels in softmax (row-constant), unused
  const float* Wv   = (const float*)d_in[14];
  const float* bv   = (const float*)d_in[15];
  const float* W1   = (const float*)d_in[16];
  const float* b1   = (const float*)d_in[17];
  const float* W2   = (const float*)d_in[18];
  const float* b2   = (const float*)d_in[19];
  const float* W3   = (const float*)d_in[20];
  const float* b3   = (const float*)d_in[21];
  float* out = (float*)d_out;

  float* F            = (float*)d_ws;
  float* wqkf         = (float*)((char*)d_ws + WS_WQK);
  float* tvec         = (float*)((char*)d_ws + WS_TVEC);
  unsigned short* pk  = (unsigned short*)((char*)d_ws + WS_PK);

  prep1_kernel<<<dim3(257), dim3(256), 0, stream>>>(Wq, Wk, bq, wqkf, tvec);
  prep2_kernel<<<dim3(364), dim3(256), 0, stream>>>(W_in, W_g1, W_g2, wqkf, pk);
  gnn_kernel<<<dim3(BB), dim3(256), 0, stream>>>(
      x, addf, src, dst, b_in, b_g1, b_g2, Wv, bv, pk, tvec, F);
  mlp_kernel<<<dim3(BB / MR), dim3(256), 0, stream>>>(
      F, W1, b1, W2, b2, W3, b3, out);
}

// Round 3
// 877.363 us; speedup vs baseline: 5.5450x; 1.7646x over previous
//
#include <hip/hip_runtime.h>
#include <math.h>

#define BB     4096
#define NN     32
#define EE     64
#define INDIM  74
#define HH     256
#define GCR    5
#define M1     1024
#define M2     512
#define FDIM   258
#define ADDD   2

typedef __attribute__((ext_vector_type(8))) short short8_t;
typedef __attribute__((ext_vector_type(4))) float float4_t;
typedef unsigned short ushort_t;

#define MFMA16(a, b, c) __builtin_amdgcn_mfma_f32_16x16x32_bf16((a), (b), (c), 0, 0, 0)

// ---- ws layout (bytes) ----
#define WS_F      0               // F [4096][258] f32 = 4,227,072
#define WS_WQK    4227072         // Wqk fp32 [256][256] = 262,144
#define WS_TVEC   4489216         // tvec fp32 [256] = 1,024
#define WS_PK     4490240         // packed bf16 hi/lo fragments
// packed offsets in ushort units from PK base:
#define PK_WIN_HI 0
#define PK_WIN_LO 24576
#define PK_G_BASE 49152
#define PK_G_STRIDE 131072
#define PK_WQK_HI 1359872
#define PK_WQK_LO (1359872 + 65536)

union U64 { unsigned long long u; unsigned short s[4]; };

__device__ __forceinline__ unsigned short f2bf(float f) {
  union { float f; unsigned int u; } c; c.f = f;
  unsigned int u = c.u;
  return (unsigned short)((u + 0x7FFFu + ((u >> 16) & 1u)) >> 16);
}
__device__ __forceinline__ float bf2f(unsigned short h) {
  union { unsigned int u; float f; } c; c.u = ((unsigned int)h) << 16;
  return c.f;
}

// element (row r, col c) of a [32][256] matrix stored in A-fragment-linear
// order (frag (mt,ks) at ushort ((ks*2+mt)*64+lane)*8): contiguous b128 reads.
__device__ __forceinline__ int fidx(int r, int c) {
  return ((c >> 5) * 2 + (r >> 4)) * 512 + ((((c >> 3) & 3) << 4) + (r & 15)) * 8 + (c & 7);
}

// ---------------------------------------------------------------------------
// Prep 1: Wqk = Wq @ Wk^T (fp32), tvec = Wk @ bq
// ---------------------------------------------------------------------------
__global__ void prep1_kernel(const float* __restrict__ Wq, const float* __restrict__ Wk,
                             const float* __restrict__ bq,
                             float* __restrict__ wqkf, float* __restrict__ tvec) {
  const int i = blockIdx.x, j = threadIdx.x;
  if (i < 256) {
    __shared__ float qrow[256];
    qrow[j] = Wq[i * 256 + j];
    __syncthreads();
    float s = 0.f;
    for (int c = 0; c < 256; ++c) s = fmaf(qrow[c], Wk[j * 256 + c], s);
    wqkf[i * 256 + j] = s;
  } else {
    float s = 0.f;
    for (int c = 0; c < 256; ++c) s = fmaf(Wk[j * 256 + c], bq[c], s);
    tvec[j] = s;
  }
}

// ---------------------------------------------------------------------------
// Prep 2: pack weights into MFMA B-fragment order, split hi/lo bf16.
// chunk: local = (nt*KS + ks)*64 + lane; elem i:
//   k = ks*32 + (lane>>4)*8 + i ; j = nt*16 + (lane&15) ; src = W[k*256+j]
// ---------------------------------------------------------------------------
template<int KS, int KREAL>
__device__ __forceinline__ void pack_one(const float* __restrict__ S,
                                         unsigned short* __restrict__ hi,
                                         unsigned short* __restrict__ lo, int local) {
  const int l = local & 63;
  const int nk = local >> 6;
  const int ks = nk % KS;
  const int nt = nk / KS;
  const int j = nt * 16 + (l & 15);
  const int kbase = ks * 32 + (l >> 4) * 8;
  short8_t h8, l8;
  #pragma unroll
  for (int i = 0; i < 8; ++i) {
    const int k = kbase + i;
    const float v = (k < KREAL) ? S[k * 256 + j] : 0.f;
    const unsigned short hb = f2bf(v);
    const unsigned short lb = f2bf(v - bf2f(hb));
    h8[i] = (short)hb; l8[i] = (short)lb;
  }
  *(short8_t*)(hi + (size_t)local * 8) = h8;
  *(short8_t*)(lo + (size_t)local * 8) = l8;
}

__global__ void prep2_kernel(const float* __restrict__ W_in,
                             const float* __restrict__ W_g1, const float* __restrict__ W_g2,
                             const float* __restrict__ wqkf, unsigned short* __restrict__ pk) {
  const int cid = blockIdx.x * 256 + threadIdx.x;
  if (cid < 3072) {
    pack_one<3, 74>(W_in, pk + PK_WIN_HI, pk + PK_WIN_LO, cid);
  } else {
    const int m = (cid - 3072) >> 13;               // 0..10
    const int local = (cid - 3072) & 8191;
    unsigned short* hi; const float* S;
    if (m < 10) {
      hi = pk + PK_G_BASE + (size_t)m * PK_G_STRIDE;
      S = (m < 5) ? (W_g1 + (size_t)m * 65536) : (W_g2 + (size_t)(m - 5) * 65536);
    } else {
      hi = pk + PK_WQK_HI;
      S = wqkf;
    }
    pack_one<8, 256>(S, hi, hi + 65536, local);
  }
}

// ---------------------------------------------------------------------------
// conv: T = h@W (MFMA1, split-bf16 3-product) ; h' = relu(Nmat@T + b) (MFMA2)
// T lives in B-frag-linear LDS; produced and consumed by the SAME wave, so
// no barrier around it. Only the in-place H overwrite needs 2 barriers.
// ---------------------------------------------------------------------------
template<int KS>
__device__ __forceinline__ void conv_mfma(
    ushort_t* Hhi, ushort_t* Hlo, ushort_t* Thi, ushort_t* Tlo,
    const ushort_t* __restrict__ Whi, const ushort_t* __restrict__ Wlo,
    const float* __restrict__ bias,
    short8_t nh0, short8_t nl0, short8_t nh1, short8_t nl1,
    int lane, int wv, bool relu)
{
  const int g4 = lane >> 4, l15 = lane & 15;

  float bc[4];
  #pragma unroll
  for (int ntl = 0; ntl < 4; ++ntl)
    bc[ntl] = bias[(wv * 4 + ntl) * 16 + l15];

  // ---- MFMA1: T = h @ W over all 256 cols (wave owns nt = wv*4 .. +3) ----
  float4_t acc[2][4];
  #pragma unroll
  for (int a = 0; a < 2; ++a)
    #pragma unroll
    for (int b = 0; b < 4; ++b) acc[a][b] = (float4_t){0.f, 0.f, 0.f, 0.f};

  #pragma unroll
  for (int ks = 0; ks < KS; ++ks) {
    const int ab0 = ((ks * 2 + 0) * 64 + lane) * 8;
    const int ab1 = ((ks * 2 + 1) * 64 + lane) * 8;
    const short8_t ah0 = *(const short8_t*)(Hhi + ab0);
    const short8_t al0 = *(const short8_t*)(Hlo + ab0);
    const short8_t ah1 = *(const short8_t*)(Hhi + ab1);
    const short8_t al1 = *(const short8_t*)(Hlo + ab1);
    #pragma unroll
    for (int ntl = 0; ntl < 4; ++ntl) {
      const int nt = wv * 4 + ntl;
      const size_t wo = ((size_t)(nt * KS + ks) * 64 + lane) * 8;
      const short8_t wh = *(const short8_t*)(Whi + wo);
      const short8_t wl = *(const short8_t*)(Wlo + wo);
      acc[0][ntl] = MFMA16(ah0, wh, acc[0][ntl]);
      acc[0][ntl] = MFMA16(ah0, wl, acc[0][ntl]);
      acc[0][ntl] = MFMA16(al0, wh, acc[0][ntl]);
      acc[1][ntl] = MFMA16(ah1, wh, acc[1][ntl]);
      acc[1][ntl] = MFMA16(ah1, wl, acc[1][ntl]);
      acc[1][ntl] = MFMA16(al1, wh, acc[1][ntl]);
    }
  }

  // ---- write T in B-frag order (4 consecutive ushorts per (mt,ntl)) ----
  #pragma unroll
  for (int mt = 0; mt < 2; ++mt) {
    const int r0 = mt * 16 + 4 * g4;
    #pragma unroll
    for (int ntl = 0; ntl < 4; ++ntl) {
      const int nt = wv * 4 + ntl;
      const int id0 = nt * 512 + ((r0 >> 3) * 16 + l15) * 8 + (r0 & 7);
      U64 ph, pl;
      #pragma unroll
      for (int jj = 0; jj < 4; ++jj) {
        const float v = acc[mt][ntl][jj];
        const unsigned short hb = f2bf(v);
        ph.s[jj] = hb;
        pl.s[jj] = f2bf(v - bf2f(hb));
      }
      *(unsigned long long*)(Thi + id0) = ph.u;
      *(unsigned long long*)(Tlo + id0) = pl.u;
    }
  }

  // ---- MFMA2: h'raw = Nmat @ T (same-wave T; hw waitcnt only) ----
  float4_t d2[2][4];
  #pragma unroll
  for (int a = 0; a < 2; ++a)
    #pragma unroll
    for (int b = 0; b < 4; ++b) d2[a][b] = (float4_t){0.f, 0.f, 0.f, 0.f};

  #pragma unroll
  for (int ntl = 0; ntl < 4; ++ntl) {
    const int nt = wv * 4 + ntl;
    const int tb = (nt * 64 + lane) * 8;
    const short8_t th = *(const short8_t*)(Thi + tb);
    const short8_t tl = *(const short8_t*)(Tlo + tb);
    d2[0][ntl] = MFMA16(nh0, th, d2[0][ntl]);
    d2[0][ntl] = MFMA16(nh0, tl, d2[0][ntl]);
    d2[0][ntl] = MFMA16(nl0, th, d2[0][ntl]);
    d2[1][ntl] = MFMA16(nh1, th, d2[1][ntl]);
    d2[1][ntl] = MFMA16(nh1, tl, d2[1][ntl]);
    d2[1][ntl] = MFMA16(nl1, th, d2[1][ntl]);
  }

  __syncthreads();   // all waves' MFMA1 H-reads complete before overwrite

  #pragma unroll
  for (int mt = 0; mt < 2; ++mt)
    #pragma unroll
    for (int ntl = 0; ntl < 4; ++ntl) {
      const int c = (wv * 4 + ntl) * 16 + l15;
      #pragma unroll
      for (int jj = 0; jj < 4; ++jj) {
        const int r = mt * 16 + 4 * g4 + jj;
        float v = d2[mt][ntl][jj] + bc[ntl];
        if (relu) v = fmaxf(v, 0.f);
        const int id = fidx(r, c);
        const unsigned short hb = f2bf(v);
        Hhi[id] = hb;
        Hlo[id] = f2bf(v - bf2f(hb));
      }
    }
  __syncthreads();   // new h visible to all waves
}

// ---------------------------------------------------------------------------
// GNN kernel. LDS: Hhi/Hlo/Thi/Tlo 16 KB each (frag-linear) + Sb 4.4 KB.
// Sb overlay: [0..1024) Nf (setup) -> S 32x33 (attn); [1056..1088) inorm -> v;
// [1088..1120) onorm -> w.
// ---------------------------------------------------------------------------
__global__ __launch_bounds__(256, 2)
void gnn_kernel(const float* __restrict__ x, const float* __restrict__ addf,
                const int* __restrict__ src, const int* __restrict__ dst,
                const float* __restrict__ b_in,
                const float* __restrict__ b_g1, const float* __restrict__ b_g2,
                const float* __restrict__ Wvp, const float* __restrict__ bv,
                const unsigned short* __restrict__ pk,
                const float* __restrict__ tvec,
                float* __restrict__ F)
{
  __shared__ __align__(16) ushort_t Hhi[8192];
  __shared__ __align__(16) ushort_t Hlo[8192];
  __shared__ __align__(16) ushort_t Thi[8192];
  __shared__ __align__(16) ushort_t Tlo[8192];
  __shared__ float Sb[1120];

  float* Nf = Sb;                  // [32][32] (setup), later S [32][33] region
  float* inormS = Sb + 1056;       // later v
  float* onormS = Sb + 1088;       // later w
  float* vS = Sb + 1056;
  float* wS = Sb + 1088;

  const int tid = threadIdx.x;
  const int lane = tid & 63;
  const int wv = tid >> 6;
  const int g4 = lane >> 4, l15 = lane & 15;
  const int g = blockIdx.x;

  // ---- build Nmat = diag(inorm) . A_adj . diag(onorm) ----
  for (int i = tid; i < 1024; i += 256) Nf[i] = 0.f;
  __syncthreads();
  if (tid < EE) {
    const int es = src[(size_t)g * EE + tid];
    const int ed = dst[(size_t)g * EE + tid];
    atomicAdd(&Nf[ed * 32 + es], 1.0f);
  }
  __syncthreads();
  if (tid < NN) {
    float s = 0.f;
    for (int n = 0; n < NN; ++n) s += Nf[tid * 32 + n];
    inormS[tid] = 1.f / sqrtf(fmaxf(s, 1.f));
  } else if (tid < 2 * NN) {
    const int n = tid - NN;
    float s = 0.f;
    for (int m = 0; m < NN; ++m) s += Nf[m * 32 + n];
    onormS[n] = 1.f / sqrtf(fmaxf(s, 1.f));
  }
  __syncthreads();
  for (int i = tid; i < 1024; i += 256)
    Nf[i] *= inormS[i >> 5] * onormS[i & 31];
  __syncthreads();

  // ---- each wave keeps Nmat A-frags (mt=0,1) in registers, split hi/lo ----
  short8_t nh0, nl0, nh1, nl1;
  #pragma unroll
  for (int i = 0; i < 8; ++i) {
    const float v0 = Nf[l15 * 32 + g4 * 8 + i];
    const unsigned short h0 = f2bf(v0);
    nh0[i] = (short)h0; nl0[i] = (short)f2bf(v0 - bf2f(h0));
    const float v1 = Nf[(16 + l15) * 32 + g4 * 8 + i];
    const unsigned short h1 = f2bf(v1);
    nh1[i] = (short)h1; nl1[i] = (short)f2bf(v1 - bf2f(h1));
  }

  // ---- stage raw x into H (frag-linear, cols 74..95 zero) ----
  for (int i = tid; i < NN * 96; i += 256) {
    const int r = i / 96, c = i - r * 96;
    const float vx = (c < INDIM) ? x[(size_t)g * (NN * INDIM) + r * INDIM + c] : 0.f;
    const int id = fidx(r, c);
    const unsigned short hb = f2bf(vx);
    Hhi[id] = hb;
    Hlo[id] = f2bf(vx - bf2f(hb));
  }
  __syncthreads();

  // ---- 11 graph convolutions ----
  conv_mfma<3>(Hhi, Hlo, Thi, Tlo, pk + PK_WIN_HI, pk + PK_WIN_LO, b_in,
               nh0, nl0, nh1, nl1, lane, wv, false);
  #pragma unroll 1
  for (int L = 0; L < GCR; ++L) {
    const unsigned short* h1 = pk + PK_G_BASE + (size_t)L * PK_G_STRIDE;
    conv_mfma<8>(Hhi, Hlo, Thi, Tlo, h1, h1 + 65536, b_g1 + L * HH,
                 nh0, nl0, nh1, nl1, lane, wv, true);
    const unsigned short* h2 = pk + PK_G_BASE + (size_t)(5 + L) * PK_G_STRIDE;
    conv_mfma<8>(Hhi, Hlo, Thi, Tlo, h2, h2 + 65536, b_g2 + L * HH,
                 nh0, nl0, nh1, nl1, lane, wv, true);
  }

  // ---- attention: u' = h@Wqk + tvec (into T, A-frag layout) ----
  {
    const unsigned short* Qhi = pk + PK_WQK_HI;
    const unsigned short* Qlo = pk + PK_WQK_LO;
    float tv4[4];
    #pragma unroll
    for (int ntl = 0; ntl < 4; ++ntl)
      tv4[ntl] = tvec[(wv * 4 + ntl) * 16 + l15];

    float4_t ua[2][4];
    #pragma unroll
    for (int a = 0; a < 2; ++a)
      #pragma unroll
      for (int b = 0; b < 4; ++b) ua[a][b] = (float4_t){0.f, 0.f, 0.f, 0.f};

    #pragma unroll
    for (int ks = 0; ks < 8; ++ks) {
      const int ab0 = ((ks * 2 + 0) * 64 + lane) * 8;
      const int ab1 = ((ks * 2 + 1) * 64 + lane) * 8;
      const short8_t ah0 = *(const short8_t*)(Hhi + ab0);
      const short8_t al0 = *(const short8_t*)(Hlo + ab0);
      const short8_t ah1 = *(const short8_t*)(Hhi + ab1);
      const short8_t al1 = *(const short8_t*)(Hlo + ab1);
      #pragma unroll
      for (int ntl = 0; ntl < 4; ++ntl) {
        const int nt = wv * 4 + ntl;
        const size_t wo = ((size_t)(nt * 8 + ks) * 64 + lane) * 8;
        const short8_t qh = *(const short8_t*)(Qhi + wo);
        const short8_t ql = *(const short8_t*)(Qlo + wo);
        ua[0][ntl] = MFMA16(ah0, qh, ua[0][ntl]);
        ua[0][ntl] = MFMA16(ah0, ql, ua[0][ntl]);
        ua[0][ntl] = MFMA16(al0, qh, ua[0][ntl]);
        ua[1][ntl] = MFMA16(ah1, qh, ua[1][ntl]);
        ua[1][ntl] = MFMA16(ah1, ql, ua[1][ntl]);
        ua[1][ntl] = MFMA16(al1, qh, ua[1][ntl]);
      }
    }
    #pragma unroll
    for (int mt = 0; mt < 2; ++mt)
      #pragma unroll
      for (int ntl = 0; ntl < 4; ++ntl) {
        const int c = (wv * 4 + ntl) * 16 + l15;
        #pragma unroll
        for (int jj = 0; jj < 4; ++jj) {
          const int r = mt * 16 + 4 * g4 + jj;
          const float v = ua[mt][ntl][jj] + tv4[ntl];
          const int id = fidx(r, c);
          const unsigned short hb = f2bf(v);
          Thi[id] = hb;
          Tlo[id] = f2bf(v - bf2f(hb));
        }
      }
  }
  __syncthreads();

  // ---- S = u' @ h^T  (h A-frags double as S's B-frags) ----
  {
    const int smt = wv >> 1, snt = wv & 1;
    float4_t sacc = (float4_t){0.f, 0.f, 0.f, 0.f};
    #pragma unroll
    for (int ks = 0; ks < 8; ++ks) {
      const int au = ((ks * 2 + smt) * 64 + lane) * 8;
      const short8_t uh = *(const short8_t*)(Thi + au);
      const short8_t ul = *(const short8_t*)(Tlo + au);
      const int ah = ((ks * 2 + snt) * 64 + lane) * 8;
      const short8_t hh = *(const short8_t*)(Hhi + ah);
      const short8_t hl = *(const short8_t*)(Hlo + ah);
      sacc = MFMA16(uh, hh, sacc);
      sacc = MFMA16(uh, hl, sacc);
      sacc = MFMA16(ul, hh, sacc);
    }
    #pragma unroll
    for (int jj = 0; jj < 4; ++jj) {
      const int r = smt * 16 + 4 * g4 + jj;
      const int c = snt * 16 + l15;
      Sb[r * 33 + c] = sacc[jj];
    }
  }

  // ---- v[m] = h[m].Wv + bv (8 lanes/row, shfl reduce) ----
  {
    const int row = tid >> 3;
    const int c0 = (tid & 7) * 32;
    float s = 0.f;
    #pragma unroll
    for (int cb = 0; cb < 32; cb += 4) {
      const float4 w4 = *(const float4*)&Wvp[c0 + cb];
      #pragma unroll
      for (int k = 0; k < 4; ++k) {
        const int c = c0 + cb + k;
        const int id = fidx(row, c);
        const float hv = bf2f(Hhi[id]) + bf2f(Hlo[id]);
        s = fmaf(hv, ((const float*)&w4)[k], s);
      }
    }
    s += __shfl_xor(s, 1); s += __shfl_xor(s, 2); s += __shfl_xor(s, 4);
    __syncthreads();            // S fully written; inormS dead
    if ((tid & 7) == 0) vS[row] = s + bv[0];
  }
  __syncthreads();

  // ---- row softmax fused with w = attn @ v ----
  if (tid < NN) {
    float mx = -1e30f;
    #pragma unroll 1
    for (int m = 0; m < NN; ++m) mx = fmaxf(mx, Sb[tid * 33 + m]);
    float se = 0.f, sv = 0.f;
    #pragma unroll 1
    for (int m = 0; m < NN; ++m) {
      const float e = expf(Sb[tid * 33 + m] - mx);
      se += e;
      sv = fmaf(e, vS[m], sv);
    }
    wS[tid] = sv / se;
  }
  __syncthreads();

  // ---- feats = h^T @ w ----
  {
    float f = 0.f;
    #pragma unroll
    for (int m = 0; m < NN; ++m) {
      const int id = fidx(m, tid);
      const float hv = bf2f(Hhi[id]) + bf2f(Hlo[id]);
      f = fmaf(hv, wS[m], f);
    }
    F[(size_t)g * FDIM + tid] = f;
    if (tid < ADDD) F[(size_t)g * FDIM + HH + tid] = addf[(size_t)g * ADDD + tid];
  }
}

// ---------------------------------------------------------------------------
// Kernel 2: batched MLP (unchanged)
// ---------------------------------------------------------------------------
#define MR 8
__global__ __launch_bounds__(256, 2)
void mlp_kernel(const float* __restrict__ F,
                const float* __restrict__ W1, const float* __restrict__ b1,
                const float* __restrict__ W2, const float* __restrict__ b2,
                const float* __restrict__ W3, const float* __restrict__ b3,
                float* __restrict__ out)
{
  __shared__ float sm[MR * M1];
  const int tid = threadIdx.x;
  const int r0 = blockIdx.x * MR;

  for (int idx = tid; idx < MR * FDIM; idx += 256) {
    const int r = idx / FDIM, c = idx - r * FDIM;
    sm[r * 260 + c] = F[(size_t)(r0 + r) * FDIM + c];
  }
  __syncthreads();

  float a1[4][MR];
  #pragma unroll
  for (int qg = 0; qg < 4; ++qg)
    #pragma unroll
    for (int r = 0; r < MR; ++r) a1[qg][r] = 0.f;
  for (int i = 0; i < FDIM; ++i) {
    float w[4];
    #pragma unroll
    for (int qg = 0; qg < 4; ++qg) w[qg] = W1[(size_t)i * M1 + tid + 256 * qg];
    #pragma unroll
    for (int r = 0; r < MR; ++r) {
      const float fv = sm[r * 260 + i];
      #pragma unroll
      for (int qg = 0; qg < 4; ++qg) a1[qg][r] = fmaf(fv, w[qg], a1[qg][r]);
    }
  }
  __syncthreads();
  #pragma unroll
  for (int qg = 0; qg < 4; ++qg) {
    const float bb = b1[tid + 256 * qg];
    #pragma unroll
    for (int r = 0; r < MR; ++r) {
      const float z = a1[qg][r] + bb;
      sm[r * M1 + tid + 256 * qg] = fmaxf(z, 0.01f * z);
    }
  }
  __syncthreads();

  float a2[2][MR];
  #pragma unroll
  for (int qg = 0; qg < 2; ++qg)
    #pragma unroll
    for (int r = 0; r < MR; ++r) a2[qg][r] = 0.f;
  for (int i = 0; i < M1; ++i) {
    float w[2];
    #pragma unroll
    for (int qg = 0; qg < 2; ++qg) w[qg] = W2[(size_t)i * M2 + tid + 256 * qg];
    #pragma unroll
    for (int r = 0; r < MR; ++r) {
      const float zv = sm[r * M1 + i];
      #pragma unroll
      for (int qg = 0; qg < 2; ++qg) a2[qg][r] = fmaf(zv, w[qg], a2[qg][r]);
    }
  }
  __syncthreads();
  #pragma unroll
  for (int qg = 0; qg < 2; ++qg) {
    const float bb = b2[tid + 256 * qg];
    #pragma unroll
    for (int r = 0; r < MR; ++r) {
      const float z = a2[qg][r] + bb;
      sm[r * M2 + tid + 256 * qg] = fmaxf(z, 0.01f * z);
    }
  }
  __syncthreads();

  const int lane = tid & 63, wid = tid >> 6;
  float wreg[8];
  #pragma unroll
  for (int q = 0; q < 8; ++q) wreg[q] = W3[lane + 64 * q];
  #pragma unroll
  for (int rr = 0; rr < 2; ++rr) {
    const int r = wid * 2 + rr;
    float s = 0.f;
    #pragma unroll
    for (int q = 0; q < 8; ++q) s = fmaf(sm[r * M2 + lane + 64 * q], wreg[q], s);
    #pragma unroll
    for (int off = 32; off; off >>= 1) s += __shfl_down(s, off);
    if (lane == 0) out[r0 + r] = s + b3[0];
  }
}

// ---------------------------------------------------------------------------
extern "C" void kernel_launch(void* const* d_in, const int* in_sizes, int n_in,
                              void* d_out, int out_size, void* d_ws, size_t ws_size,
                              hipStream_t stream) {
  (void)in_sizes; (void)n_in; (void)out_size; (void)ws_size;
  const float* x    = (const float*)d_in[0];
  const float* addf = (const float*)d_in[1];
  const int*   src  = (const int*)d_in[2];
  const int*   dst  = (const int*)d_in[3];
  const float* W_in = (const float*)d_in[4];
  const float* b_in = (const float*)d_in[5];
  const float* W_g1 = (const float*)d_in[6];
  const float* b_g1 = (const float*)d_in[7];
  const float* W_g2 = (const float*)d_in[8];
  const float* b_g2 = (const float*)d_in[9];
  const float* Wq   = (const float*)d_in[10];
  const float* bq   = (const float*)d_in[11];
  const float* Wk   = (const float*)d_in[12];
  // d_in[13] = bk : cancels in softmax (row-constant), unused
  const float* Wv   = (const float*)d_in[14];
  const float* bv   = (const float*)d_in[15];
  const float* W1   = (const float*)d_in[16];
  const float* b1   = (const float*)d_in[17];
  const float* W2   = (const float*)d_in[18];
  const float* b2   = (const float*)d_in[19];
  const float* W3   = (const float*)d_in[20];
  const float* b3   = (const float*)d_in[21];
  float* out = (float*)d_out;

  float* F            = (float*)d_ws;
  float* wqkf         = (float*)((char*)d_ws + WS_WQK);
  float* tvec         = (float*)((char*)d_ws + WS_TVEC);
  unsigned short* pk  = (unsigned short*)((char*)d_ws + WS_PK);

  prep1_kernel<<<dim3(257), dim3(256), 0, stream>>>(Wq, Wk, bq, wqkf, tvec);
  prep2_kernel<<<dim3(364), dim3(256), 0, stream>>>(W_in, W_g1, W_g2, wqkf, pk);
  gnn_kernel<<<dim3(BB), dim3(256), 0, stream>>>(
      x, addf, src, dst, b_in, b_g1, b_g2, Wv, bv, pk, tvec, F);
  mlp_kernel<<<dim3(BB / MR), dim3(256), 0, stream>>>(
      F, W1, b1, W2, b2, W3, b3, out);
}